// Round 7
// baseline (688.070 us; speedup 1.0000x reference)
//
#include <hip/hip_runtime.h>
#include <hip/hip_fp16.h>

#define NN 100000
#define NE 1600000
#define EPSF 1e-5f

#define NB 1563        // node buckets of 64: (NN+63)/64
#define NCHUNK 256
#define CHUNK 6250     // NCHUNK * CHUNK == NE
#define CAP 2048       // per-bucket LDS edge staging (mean 1024, sigma 32)

typedef __attribute__((ext_vector_type(8))) short bf16x8;
typedef __attribute__((ext_vector_type(4))) float f32x4;

__device__ __forceinline__ ushort f2b(float f) {
    uint u = __float_as_uint(f);
    uint r = (u + 0x7FFFu + ((u >> 16) & 1u)) >> 16;
    return (ushort)r;
}
__device__ __forceinline__ float b2f(ushort h) { return __uint_as_float(((uint)h) << 16); }

// ---------------- preprocessing: two-level counting sort by dst ----------------

__global__ __launch_bounds__(256) void hist_b(const int* __restrict__ ei, int* __restrict__ part) {
    __shared__ int h[NB];
    int chunk = blockIdx.x;
    for (int i = threadIdx.x; i < NB; i += 256) h[i] = 0;
    __syncthreads();
    int base = chunk * CHUNK;
    int lim = base + CHUNK; if (lim > NE) lim = NE;
    for (int e = base + threadIdx.x; e < lim; e += 256)
        atomicAdd(&h[ei[NE + e] >> 6], 1);
    __syncthreads();
    int* p = part + (size_t)chunk * NB;
    for (int i = threadIdx.x; i < NB; i += 256) p[i] = h[i];
}

__global__ __launch_bounds__(256) void scan_chunks_b(int* __restrict__ part, int* __restrict__ cnt) {
    int b = blockIdx.x * 256 + threadIdx.x;
    if (b >= NB) return;
    int acc = 0;
    for (int c = 0; c < NCHUNK; c++) {
        int v = part[(size_t)c * NB + b];
        part[(size_t)c * NB + b] = acc;
        acc += v;
    }
    cnt[b] = acc;
}

__global__ __launch_bounds__(256) void bucket_scan(const int* __restrict__ cnt, int* __restrict__ bstart) {
    __shared__ int s[256];
    int t = threadIdx.x;
    int loc[7];
    int sum = 0;
#pragma unroll
    for (int j = 0; j < 7; j++) {
        int i = t * 7 + j;
        int v = (i < NB) ? cnt[i] : 0;
        loc[j] = sum;
        sum += v;
    }
    s[t] = sum;
    __syncthreads();
    for (int off = 1; off < 256; off <<= 1) {
        int x = (t >= off) ? s[t - off] : 0;
        __syncthreads();
        s[t] += x;
        __syncthreads();
    }
    int base = t ? s[t - 1] : 0;
#pragma unroll
    for (int j = 0; j < 7; j++) {
        int i = t * 7 + j;
        if (i < NB) bstart[i] = base + loc[j];
    }
    if (t == 0) bstart[NB] = NE;
}

__global__ __launch_bounds__(256) void place_b(const int* __restrict__ ei, const float* __restrict__ ew,
                                               const int* __restrict__ bstart, const int* __restrict__ part,
                                               uint2* __restrict__ csr) {
    __shared__ int cur[NB];
    int chunk = blockIdx.x;
    const int* p = part + (size_t)chunk * NB;
    for (int i = threadIdx.x; i < NB; i += 256) cur[i] = bstart[i] + p[i];
    __syncthreads();
    int base = chunk * CHUNK;
    int lim = base + CHUNK; if (lim > NE) lim = NE;
    for (int e = base + threadIdx.x; e < lim; e += 256) {
        int s = ei[e], d = ei[NE + e];
        float w = ew[e];
        int pos = atomicAdd(&cur[d >> 6], 1);
        csr[pos] = make_uint2((uint)s | ((uint)(d & 63) << 17), __float_as_uint(w));
    }
}

__global__ __launch_bounds__(256) void subsort(uint2* __restrict__ csr, const int* __restrict__ bstart,
                                               int* __restrict__ row, float* __restrict__ dinv) {
    __shared__ uint2 E[CAP];
    __shared__ int cnt[64];
    __shared__ int cur[64];
    __shared__ float degf[64];
    int bkt = blockIdx.x;
    int beg = bstart[bkt], end = bstart[bkt + 1];
    int m = end - beg;
    if (threadIdx.x < 64) { cnt[threadIdx.x] = 0; degf[threadIdx.x] = 0.f; }
    __syncthreads();
    for (int i = threadIdx.x; i < m; i += 256) {
        uint2 ed = csr[beg + i];
        if (i < CAP) E[i] = ed;
        int dl = (ed.x >> 17) & 63;
        atomicAdd(&cnt[dl], 1);
        atomicAdd(&degf[dl], __uint_as_float(ed.y));
    }
    __syncthreads();
    if (threadIdx.x < 64) {
        int p = 0;
        for (int j = 0; j < (int)threadIdx.x; j++) p += cnt[j];
        cur[threadIdx.x] = p;
        int node = bkt * 64 + threadIdx.x;
        if (node < NN) {
            row[node] = beg + p;
            dinv[node] = rsqrtf(degf[threadIdx.x] + 1.0f);
        }
        if (bkt == NB - 1 && threadIdx.x == 0) row[NN] = NE;
    }
    __syncthreads();
    for (int i = threadIdx.x; i < m; i += 256) {
        uint2 ed = E[i < CAP ? i : 0];
        int dl = (ed.x >> 17) & 63;
        int pos = atomicAdd(&cur[dl], 1);
        csr[beg + pos] = make_uint2(ed.x & 0x1FFFFu, ed.y);
    }
}

// build 4-byte edge records: {src:17 | fp16-weight(sans sign):15}, w = ew*dinv_s*dinv_d
__global__ __launch_bounds__(256) void norm4(const uint2* __restrict__ csr, const int* __restrict__ row,
                                             const float* __restrict__ dinv, uint* __restrict__ csr4, int n) {
    int wave = threadIdx.x >> 6, lane = threadIdx.x & 63;
    int node = blockIdx.x * 4 + wave;
    if (node >= n) return;
    int beg = row[node], end = row[node + 1];
    float di = dinv[node];
    for (int e = beg + lane; e < end; e += 64) {
        uint2 u = csr[e];
        float w = __uint_as_float(u.y) * dinv[u.x & 0x1FFFFu] * di;
        ushort hb = __half_as_ushort(__float2half(w));
        csr4[e] = (u.x & 0x1FFFFu) | ((uint)hb << 17);
    }
}

// ---------------- weight pre-pack into MFMA B-fragment layout ----------------

__global__ __launch_bounds__(256) void pack_w(const float* __restrict__ W, ushort* __restrict__ WF, int ncol) {
    int slot = blockIdx.x * 256 + threadIdx.x;
    int nc16 = ncol >> 4;
    int tot = 4 * nc16 * 64;
    if (slot >= tot) return;
    int lane = slot & 63;
    int c = (slot >> 6) % nc16;
    int ks = (slot >> 6) / nc16;
    int col = c * 16 + (lane & 15);
    int k0 = ks * 32 + (lane >> 4) * 8;
#pragma unroll
    for (int e = 0; e < 8; e++) WF[slot * 8 + e] = f2b(W[(k0 + e) * ncol + col]);
}

// ---------------- GEMM via MFMA: XWT[c][n][16] = (A[n,128] @ W) chunk-major ----------------

template <bool AF32>
__global__ __launch_bounds__(256) void gemm_mfma(const void* __restrict__ Ap, const ushort* __restrict__ WF,
                                                 ushort* __restrict__ XWT, int ngrp) {
    __shared__ ushort Bl[4 * 8 * 64 * 8];  // 32 KB
    for (int i = threadIdx.x * 8; i < 4 * 8 * 64 * 8; i += 256 * 8)
        *(bf16x8*)&Bl[i] = *(const bf16x8*)&WF[i];
    __syncthreads();
    int wave = __builtin_amdgcn_readfirstlane(threadIdx.x >> 6);
    int lane = threadIdx.x & 63;
    int rg = blockIdx.x * 4 + wave;
    if (rg >= ngrp) return;
    int r0 = rg * 16;
    int rA = r0 + (lane & 15);
    int kb = (lane >> 4) * 8;
    bf16x8 a[4];
    if (AF32) {
        const float* A = (const float*)Ap;
#pragma unroll
        for (int ks = 0; ks < 4; ks++) {
            const float* p = &A[(size_t)rA * 128 + ks * 32 + kb];
            float4 x0 = *(const float4*)p;
            float4 x1 = *(const float4*)(p + 4);
            ushort t[8] = {f2b(x0.x), f2b(x0.y), f2b(x0.z), f2b(x0.w),
                           f2b(x1.x), f2b(x1.y), f2b(x1.z), f2b(x1.w)};
            a[ks] = *(bf16x8*)t;
        }
    } else {
        const ushort* A = (const ushort*)Ap;
#pragma unroll
        for (int ks = 0; ks < 4; ks++)
            a[ks] = *(const bf16x8*)&A[(size_t)rA * 128 + ks * 32 + kb];
    }
#pragma unroll
    for (int c = 0; c < 8; c++) {
        f32x4 acc = {0.f, 0.f, 0.f, 0.f};
#pragma unroll
        for (int ks = 0; ks < 4; ks++) {
            bf16x8 b = *(const bf16x8*)&Bl[((ks * 8 + c) * 64 + lane) * 8];
            acc = __builtin_amdgcn_mfma_f32_16x16x32_bf16(a[ks], b, acc, 0, 0, 0);
        }
        int chl = lane & 15;
        int rowb = r0 + (lane >> 4) * 4;
#pragma unroll
        for (int r = 0; r < 4; r++)
            XWT[((size_t)c * NN + rowb + r) * 16 + chl] = f2b(acc[r]);
    }
}

// layer-2 GEMM, BN-affine + ReLU fused on A; emits H1 (row-major) and XWT2 (chunk-major)
__global__ __launch_bounds__(256) void gemm_mfma_bn(const ushort* __restrict__ HB, const float* __restrict__ stats,
                                                    const ushort* __restrict__ WF, ushort* __restrict__ H1,
                                                    ushort* __restrict__ XWT, int ngrp) {
    __shared__ ushort Bl[4 * 8 * 64 * 8];  // 32 KB
    __shared__ float sst[256];
    sst[threadIdx.x] = stats[threadIdx.x];
    for (int i = threadIdx.x * 8; i < 4 * 8 * 64 * 8; i += 256 * 8)
        *(bf16x8*)&Bl[i] = *(const bf16x8*)&WF[i];
    __syncthreads();
    int wave = __builtin_amdgcn_readfirstlane(threadIdx.x >> 6);
    int lane = threadIdx.x & 63;
    int rg = blockIdx.x * 4 + wave;
    if (rg >= ngrp) return;
    int r0 = rg * 16;
    int rA = r0 + (lane & 15);
    int kb = (lane >> 4) * 8;
    bf16x8 a[4];
#pragma unroll
    for (int ks = 0; ks < 4; ks++) {
        int cbase = ks * 32 + kb;
        bf16x8 u = *(const bf16x8*)&HB[(size_t)rA * 128 + cbase];
        ushort t[8];
#pragma unroll
        for (int e = 0; e < 8; e++) {
            float f = fmaxf(b2f((ushort)u[e]) * sst[cbase + e] + sst[128 + cbase + e], 0.f);
            t[e] = f2b(f);
        }
        a[ks] = *(bf16x8*)t;
        *(bf16x8*)&H1[(size_t)rA * 128 + cbase] = a[ks];
    }
#pragma unroll
    for (int c = 0; c < 8; c++) {
        f32x4 acc = {0.f, 0.f, 0.f, 0.f};
#pragma unroll
        for (int ks = 0; ks < 4; ks++) {
            bf16x8 b = *(const bf16x8*)&Bl[((ks * 8 + c) * 64 + lane) * 8];
            acc = __builtin_amdgcn_mfma_f32_16x16x32_bf16(a[ks], b, acc, 0, 0, 0);
        }
        int chl = lane & 15;
        int rowb = r0 + (lane >> 4) * 4;
#pragma unroll
        for (int r = 0; r < 4; r++)
            XWT[((size_t)c * NN + rowb + r) * 16 + chl] = f2b(acc[r]);
    }
}

// ---------------- final: OUT[n,64] = max(H1,H2) @ Wf + bf (MFMA) ----------------

__global__ __launch_bounds__(256) void final_mfma(const ushort* __restrict__ H1, const ushort* __restrict__ H2,
                                                  const ushort* __restrict__ WF, const float* __restrict__ bfv,
                                                  float* __restrict__ OUT, int ngrp) {
    __shared__ ushort Bl[4 * 4 * 64 * 8];  // 16 KB
    for (int i = threadIdx.x * 8; i < 4 * 4 * 64 * 8; i += 256 * 8)
        *(bf16x8*)&Bl[i] = *(const bf16x8*)&WF[i];
    __syncthreads();
    int wave = __builtin_amdgcn_readfirstlane(threadIdx.x >> 6);
    int lane = threadIdx.x & 63;
    int rg = blockIdx.x * 4 + wave;
    if (rg >= ngrp) return;
    int r0 = rg * 16;
    int rA = r0 + (lane & 15);
    int kb = (lane >> 4) * 8;
    bf16x8 a[4];
#pragma unroll
    for (int ks = 0; ks < 4; ks++) {
        bf16x8 u = *(const bf16x8*)&H1[(size_t)rA * 128 + ks * 32 + kb];
        bf16x8 v = *(const bf16x8*)&H2[(size_t)rA * 128 + ks * 32 + kb];
        ushort t[8];
#pragma unroll
        for (int e = 0; e < 8; e++) {
            ushort ue = (ushort)u[e], ve = (ushort)v[e];
            t[e] = (b2f(ue) >= b2f(ve)) ? ue : ve;
        }
        a[ks] = *(bf16x8*)t;
    }
#pragma unroll
    for (int c = 0; c < 4; c++) {
        f32x4 acc = {0.f, 0.f, 0.f, 0.f};
#pragma unroll
        for (int ks = 0; ks < 4; ks++) {
            bf16x8 b = *(const bf16x8*)&Bl[((ks * 4 + c) * 64 + lane) * 8];
            acc = __builtin_amdgcn_mfma_f32_16x16x32_bf16(a[ks], b, acc, 0, 0, 0);
        }
        int colb = c * 16 + (lane & 15);
        int rowb = r0 + (lane >> 4) * 4;
        float bb = bfv[colb];
#pragma unroll
        for (int r = 0; r < 4; r++)
            OUT[(size_t)(rowb + r) * 64 + colb] = acc[r] + bb;
    }
}

// ---------------- aggregation: channel-chunked, latency-tolerant ----------------
// wave = 1 node x (8 edge-slots x 8 channel-pairs); 16 edges in flight (unroll x2).
// cb = blockIdx&7 pins one 16-ch chunk (3.2 MB, L2-resident) per XCD.

__global__ __launch_bounds__(512) void aggregate_c2(const ushort* __restrict__ XWT, const int* __restrict__ row,
                                                    const uint* __restrict__ csr4, const float* __restrict__ dinv,
                                                    const float* __restrict__ bias, ushort* __restrict__ OUT) {
    int cb = blockIdx.x & 7;
    int nb = blockIdx.x >> 3;
    int wv = threadIdx.x >> 6;
    int lane = threadIdx.x & 63;
    int el = lane >> 3;          // edge slot 0..7
    int cp = lane & 7;           // channel pair 0..7
    int node = nb * 8 + wv;
    int beg = row[node], end = row[node + 1];
    const ushort* base = XWT + (size_t)cb * NN * 16;
    float ax0 = 0.f, ay0 = 0.f, ax1 = 0.f, ay1 = 0.f;
    int i = beg + el;
    for (; i + 8 < end; i += 16) {
        uint e0 = __builtin_nontemporal_load(&csr4[i]);
        uint e1 = __builtin_nontemporal_load(&csr4[i + 8]);
        uint v0 = *(const uint*)&base[(size_t)(e0 & 0x1FFFFu) * 16 + cp * 2];
        uint v1 = *(const uint*)&base[(size_t)(e1 & 0x1FFFFu) * 16 + cp * 2];
        float w0 = __half2float(__ushort_as_half((ushort)(e0 >> 17)));
        float w1 = __half2float(__ushort_as_half((ushort)(e1 >> 17)));
        ax0 += w0 * __uint_as_float(v0 << 16);
        ay0 += w0 * __uint_as_float(v0 & 0xFFFF0000u);
        ax1 += w1 * __uint_as_float(v1 << 16);
        ay1 += w1 * __uint_as_float(v1 & 0xFFFF0000u);
    }
    if (i < end) {
        uint e0 = __builtin_nontemporal_load(&csr4[i]);
        uint v0 = *(const uint*)&base[(size_t)(e0 & 0x1FFFFu) * 16 + cp * 2];
        float w0 = __half2float(__ushort_as_half((ushort)(e0 >> 17)));
        ax0 += w0 * __uint_as_float(v0 << 16);
        ay0 += w0 * __uint_as_float(v0 & 0xFFFF0000u);
    }
    float ax = ax0 + ax1, ay = ay0 + ay1;
    ax += __shfl_xor(ax, 8);  ay += __shfl_xor(ay, 8);
    ax += __shfl_xor(ax, 16); ay += __shfl_xor(ay, 16);
    ax += __shfl_xor(ax, 32); ay += __shfl_xor(ay, 32);
    if (el == 0) {
        float di = dinv[node];
        float sl = di * di;
        uint vs = *(const uint*)&base[(size_t)node * 16 + cp * 2];
        float2 b = *(const float2*)&bias[cb * 16 + cp * 2];
        float ox = ax + sl * __uint_as_float(vs << 16) + b.x;
        float oy = ay + sl * __uint_as_float(vs & 0xFFFF0000u) + b.y;
        uint o = (uint)f2b(ox) | ((uint)f2b(oy) << 16);
        *(uint*)&OUT[(size_t)node * 128 + cb * 16 + cp * 2] = o;
    }
}

// ---------------- BatchNorm stats ----------------

__global__ __launch_bounds__(256) void bn_stats_b(const ushort* __restrict__ H, float* __restrict__ part, int n) {
    int wave = threadIdx.x >> 6;
    int lane = threadIdx.x & 63;
    float2 s = make_float2(0.f, 0.f), q = make_float2(0.f, 0.f);
    for (int r = blockIdx.x * 4 + wave; r < n; r += gridDim.x * 4) {
        uint v = *(const uint*)&H[(size_t)r * 128 + lane * 2];
        float x = __uint_as_float(v << 16);
        float y = __uint_as_float(v & 0xFFFF0000u);
        s.x += x; s.y += y;
        q.x += x * x; q.y += y * y;
    }
    __shared__ float2 reds[4][64];
    __shared__ float2 redq[4][64];
    reds[wave][lane] = s;
    redq[wave][lane] = q;
    __syncthreads();
    if (threadIdx.x < 64) {
        int l = threadIdx.x;
        float2 S = make_float2(0.f, 0.f), Q = make_float2(0.f, 0.f);
#pragma unroll
        for (int w = 0; w < 4; w++) {
            S.x += reds[w][l].x; S.y += reds[w][l].y;
            Q.x += redq[w][l].x; Q.y += redq[w][l].y;
        }
        part[blockIdx.x * 256 + l * 2 + 0] = S.x;
        part[blockIdx.x * 256 + l * 2 + 1] = S.y;
        part[blockIdx.x * 256 + 128 + l * 2 + 0] = Q.x;
        part[blockIdx.x * 256 + 128 + l * 2 + 1] = Q.y;
    }
}

// parallel final reduction: 1024 threads = 128 channels x 8 groups
__global__ __launch_bounds__(1024) void bn_final2(const float* __restrict__ part, const float* __restrict__ gamma,
                                                  const float* __restrict__ beta, float* __restrict__ stats,
                                                  float invN) {
    int c = threadIdx.x & 127;
    int g = threadIdx.x >> 7;
    float s = 0.f, q = 0.f;
#pragma unroll 8
    for (int b = g; b < 512; b += 8) {
        s += part[b * 256 + c];
        q += part[b * 256 + 128 + c];
    }
    __shared__ float red[8][256];
    red[g][c] = s;
    red[g][128 + c] = q;
    __syncthreads();
    __shared__ float fin[256];
    if (threadIdx.x < 256) {
        float acc = 0.f;
#pragma unroll
        for (int gg = 0; gg < 8; gg++) acc += red[gg][threadIdx.x];
        fin[threadIdx.x] = acc;
    }
    __syncthreads();
    if (threadIdx.x < 128) {
        float mu = fin[c] * invN;
        float var = fin[128 + c] * invN - mu * mu;
        float sc = gamma[c] * rsqrtf(var + EPSF);
        stats[c] = sc;
        stats[128 + c] = beta[c] - mu * sc;
    }
}

// ---------------- launch ----------------

extern "C" void kernel_launch(void* const* d_in, const int* in_sizes, int n_in,
                              void* d_out, int out_size, void* d_ws, size_t ws_size,
                              hipStream_t stream) {
    const float* x     = (const float*)d_in[0];
    const int*   ei    = (const int*)  d_in[1];
    const float* ew    = (const float*)d_in[2];
    const float* W1    = (const float*)d_in[3];
    const float* b1    = (const float*)d_in[4];
    const float* gamma = (const float*)d_in[5];
    const float* beta  = (const float*)d_in[6];
    const float* W2    = (const float*)d_in[7];
    const float* b2    = (const float*)d_in[8];
    const float* Wf    = (const float*)d_in[9];
    const float* bf    = (const float*)d_in[10];
    float* out = (float*)d_out;

    char* ws = (char*)d_ws;
    size_t off = 0;
    auto alloc = [&](size_t bytes) {
        void* p = ws + off;
        off += (bytes + 1023) & ~(size_t)1023;
        return p;
    };
    ushort* XWT  = (ushort*)alloc((size_t)NN * 128 * 2);  // chunk-major [8][NN][16]; aliased as PART pre-GEMM
    ushort* HB   = (ushort*)alloc((size_t)NN * 128 * 2);
    ushort* H1B  = (ushort*)alloc((size_t)NN * 128 * 2);
    ushort* H2B  = (ushort*)alloc((size_t)NN * 128 * 2);
    float*  DINV = (float*) alloc((size_t)NN * 4);
    int*    ROW  = (int*)   alloc((size_t)(NN + 1) * 4);
    int*    CNT  = (int*)   alloc((size_t)NB * 4);
    int*    BSTART = (int*) alloc((size_t)(NB + 1) * 4);
    uint2*  CSR8 = (uint2*) alloc((size_t)NE * 8);
    uint*   CSR4 = (uint*)  alloc((size_t)NE * 4);
    float*  PARTBN = (float*)alloc((size_t)512 * 256 * 4);
    float*  STAT = (float*) alloc(1024);
    ushort* WF1  = (ushort*)alloc((size_t)4 * 8 * 64 * 8 * 2);
    ushort* WF2  = (ushort*)alloc((size_t)4 * 8 * 64 * 8 * 2);
    ushort* WFF  = (ushort*)alloc((size_t)4 * 4 * 64 * 8 * 2);
    int* PART = (int*)XWT;   // 1.6 MB alias, used only pre-GEMM

    int ngrp = NN / 16;               // 6250
    int gblocks = (ngrp + 3) / 4;     // 1563
    int ablocks = (NN / 8) * 8;       // 100000: (node-octets) x (channel-chunks)

    // ---- two-level counting sort (bucket=node>>6), zero global atomics ----
    hist_b<<<NCHUNK, 256, 0, stream>>>(ei, PART);
    scan_chunks_b<<<(NB + 255) / 256, 256, 0, stream>>>(PART, CNT);
    bucket_scan<<<1, 256, 0, stream>>>(CNT, BSTART);
    place_b<<<NCHUNK, 256, 0, stream>>>(ei, ew, BSTART, PART, CSR8);
    subsort<<<NB, 256, 0, stream>>>(CSR8, BSTART, ROW, DINV);
    norm4<<<(NN + 3) / 4, 256, 0, stream>>>(CSR8, ROW, DINV, CSR4, NN);

    pack_w<<<8, 256, 0, stream>>>(W1, WF1, 128);
    pack_w<<<8, 256, 0, stream>>>(W2, WF2, 128);
    pack_w<<<4, 256, 0, stream>>>(Wf, WFF, 64);

    // layer 1
    gemm_mfma<true><<<gblocks, 256, 0, stream>>>(x, WF1, XWT, ngrp);
    aggregate_c2<<<ablocks, 512, 0, stream>>>(XWT, ROW, CSR4, DINV, b1, HB);
    bn_stats_b<<<512, 256, 0, stream>>>(HB, PARTBN, NN);
    bn_final2<<<1, 1024, 0, stream>>>(PARTBN, gamma, beta, STAT, 1.0f / NN);

    // layer 2 (BN+ReLU fused into A-load; emits H1B row-major and XWT2 chunk-major)
    gemm_mfma_bn<<<gblocks, 256, 0, stream>>>(HB, STAT, WF2, H1B, XWT, ngrp);
    aggregate_c2<<<ablocks, 512, 0, stream>>>(XWT, ROW, CSR4, DINV, b2, H2B);

    // JK max + final projection
    final_mfma<<<gblocks, 256, 0, stream>>>(H1B, H2B, WFF, bf, out, ngrp);
}

// Round 8
// 283.548 us; speedup vs baseline: 2.4266x; 2.4266x over previous
//
#include <hip/hip_runtime.h>
#include <hip/hip_fp16.h>

#define NN 100000
#define NE 1600000
#define EPSF 1e-5f

#define NB 1563        // node buckets of 64: (NN+63)/64
#define NCHUNK 256
#define CHUNK 6250     // NCHUNK * CHUNK == NE
#define CAP 2048       // per-bucket LDS edge staging (mean 1024, sigma 32)

typedef __attribute__((ext_vector_type(8))) short bf16x8;
typedef __attribute__((ext_vector_type(4))) float f32x4;

__device__ __forceinline__ ushort f2b(float f) {
    uint u = __float_as_uint(f);
    uint r = (u + 0x7FFFu + ((u >> 16) & 1u)) >> 16;
    return (ushort)r;
}
__device__ __forceinline__ float b2f(ushort h) { return __uint_as_float(((uint)h) << 16); }

// ---------------- preprocessing: two-level counting sort by dst ----------------

__global__ __launch_bounds__(256) void hist_b(const int* __restrict__ ei, int* __restrict__ part) {
    __shared__ int h[NB];
    int chunk = blockIdx.x;
    for (int i = threadIdx.x; i < NB; i += 256) h[i] = 0;
    __syncthreads();
    int base = chunk * CHUNK;
    int lim = base + CHUNK; if (lim > NE) lim = NE;
    for (int e = base + threadIdx.x; e < lim; e += 256)
        atomicAdd(&h[ei[NE + e] >> 6], 1);
    __syncthreads();
    int* p = part + (size_t)chunk * NB;
    for (int i = threadIdx.x; i < NB; i += 256) p[i] = h[i];
}

__global__ __launch_bounds__(256) void scan_chunks_b(int* __restrict__ part, int* __restrict__ cnt) {
    int b = blockIdx.x * 256 + threadIdx.x;
    if (b >= NB) return;
    int acc = 0;
    for (int c = 0; c < NCHUNK; c++) {
        int v = part[(size_t)c * NB + b];
        part[(size_t)c * NB + b] = acc;
        acc += v;
    }
    cnt[b] = acc;
}

__global__ __launch_bounds__(256) void bucket_scan(const int* __restrict__ cnt, int* __restrict__ bstart) {
    __shared__ int s[256];
    int t = threadIdx.x;
    int loc[7];
    int sum = 0;
#pragma unroll
    for (int j = 0; j < 7; j++) {
        int i = t * 7 + j;
        int v = (i < NB) ? cnt[i] : 0;
        loc[j] = sum;
        sum += v;
    }
    s[t] = sum;
    __syncthreads();
    for (int off = 1; off < 256; off <<= 1) {
        int x = (t >= off) ? s[t - off] : 0;
        __syncthreads();
        s[t] += x;
        __syncthreads();
    }
    int base = t ? s[t - 1] : 0;
#pragma unroll
    for (int j = 0; j < 7; j++) {
        int i = t * 7 + j;
        if (i < NB) bstart[i] = base + loc[j];
    }
    if (t == 0) bstart[NB] = NE;
}

__global__ __launch_bounds__(256) void place_b(const int* __restrict__ ei, const float* __restrict__ ew,
                                               const int* __restrict__ bstart, const int* __restrict__ part,
                                               uint2* __restrict__ csr) {
    __shared__ int cur[NB];
    int chunk = blockIdx.x;
    const int* p = part + (size_t)chunk * NB;
    for (int i = threadIdx.x; i < NB; i += 256) cur[i] = bstart[i] + p[i];
    __syncthreads();
    int base = chunk * CHUNK;
    int lim = base + CHUNK; if (lim > NE) lim = NE;
    for (int e = base + threadIdx.x; e < lim; e += 256) {
        int s = ei[e], d = ei[NE + e];
        float w = ew[e];
        int pos = atomicAdd(&cur[d >> 6], 1);
        csr[pos] = make_uint2((uint)s | ((uint)(d & 63) << 17), __float_as_uint(w));
    }
}

__global__ __launch_bounds__(256) void subsort(uint2* __restrict__ csr, const int* __restrict__ bstart,
                                               int* __restrict__ row, float* __restrict__ dinv) {
    __shared__ uint2 E[CAP];
    __shared__ int cnt[64];
    __shared__ int cur[64];
    __shared__ float degf[64];
    int bkt = blockIdx.x;
    int beg = bstart[bkt], end = bstart[bkt + 1];
    int m = end - beg;
    if (threadIdx.x < 64) { cnt[threadIdx.x] = 0; degf[threadIdx.x] = 0.f; }
    __syncthreads();
    for (int i = threadIdx.x; i < m; i += 256) {
        uint2 ed = csr[beg + i];
        if (i < CAP) E[i] = ed;
        int dl = (ed.x >> 17) & 63;
        atomicAdd(&cnt[dl], 1);
        atomicAdd(&degf[dl], __uint_as_float(ed.y));
    }
    __syncthreads();
    if (threadIdx.x < 64) {
        int p = 0;
        for (int j = 0; j < (int)threadIdx.x; j++) p += cnt[j];
        cur[threadIdx.x] = p;
        int node = bkt * 64 + threadIdx.x;
        if (node < NN) {
            row[node] = beg + p;
            dinv[node] = rsqrtf(degf[threadIdx.x] + 1.0f);
        }
        if (bkt == NB - 1 && threadIdx.x == 0) row[NN] = NE;
    }
    __syncthreads();
    for (int i = threadIdx.x; i < m; i += 256) {
        uint2 ed = E[i < CAP ? i : 0];
        int dl = (ed.x >> 17) & 63;
        int pos = atomicAdd(&cur[dl], 1);
        csr[beg + pos] = make_uint2(ed.x & 0x1FFFFu, ed.y);
    }
}

// build 4-byte edge records: {src:17 | fp16-weight(positive, 15 bits):15}
__global__ __launch_bounds__(256) void norm4(const uint2* __restrict__ csr, const int* __restrict__ row,
                                             const float* __restrict__ dinv, uint* __restrict__ csr4, int n) {
    int wave = threadIdx.x >> 6, lane = threadIdx.x & 63;
    int node = blockIdx.x * 4 + wave;
    if (node >= n) return;
    int beg = row[node], end = row[node + 1];
    float di = dinv[node];
    for (int e = beg + lane; e < end; e += 64) {
        uint2 u = csr[e];
        float w = __uint_as_float(u.y) * dinv[u.x & 0x1FFFFu] * di;
        ushort hb = __half_as_ushort(__float2half(w));
        csr4[e] = (u.x & 0x1FFFFu) | ((uint)hb << 17);
    }
}

// ---------------- weight pre-pack into MFMA B-fragment layout ----------------

__global__ __launch_bounds__(256) void pack_w(const float* __restrict__ W, ushort* __restrict__ WF, int ncol) {
    int slot = blockIdx.x * 256 + threadIdx.x;
    int nc16 = ncol >> 4;
    int tot = 4 * nc16 * 64;
    if (slot >= tot) return;
    int lane = slot & 63;
    int c = (slot >> 6) % nc16;
    int ks = (slot >> 6) / nc16;
    int col = c * 16 + (lane & 15);
    int k0 = ks * 32 + (lane >> 4) * 8;
#pragma unroll
    for (int e = 0; e < 8; e++) WF[slot * 8 + e] = f2b(W[(k0 + e) * ncol + col]);
}

// ---------------- GEMM via MFMA: C[n,128] = A[n,128] @ W (row-major out) ----------------

template <bool AF32>
__global__ __launch_bounds__(256) void gemm_mfma(const void* __restrict__ Ap, const ushort* __restrict__ WF,
                                                 ushort* __restrict__ C, int ngrp) {
    __shared__ ushort Bl[4 * 8 * 64 * 8];  // 32 KB
    for (int i = threadIdx.x * 8; i < 4 * 8 * 64 * 8; i += 256 * 8)
        *(bf16x8*)&Bl[i] = *(const bf16x8*)&WF[i];
    __syncthreads();
    int wave = __builtin_amdgcn_readfirstlane(threadIdx.x >> 6);
    int lane = threadIdx.x & 63;
    int rg = blockIdx.x * 4 + wave;
    if (rg >= ngrp) return;
    int r0 = rg * 16;
    int rA = r0 + (lane & 15);
    int kb = (lane >> 4) * 8;
    bf16x8 a[4];
    if (AF32) {
        const float* A = (const float*)Ap;
#pragma unroll
        for (int ks = 0; ks < 4; ks++) {
            const float* p = &A[(size_t)rA * 128 + ks * 32 + kb];
            float4 x0 = *(const float4*)p;
            float4 x1 = *(const float4*)(p + 4);
            ushort t[8] = {f2b(x0.x), f2b(x0.y), f2b(x0.z), f2b(x0.w),
                           f2b(x1.x), f2b(x1.y), f2b(x1.z), f2b(x1.w)};
            a[ks] = *(bf16x8*)t;
        }
    } else {
        const ushort* A = (const ushort*)Ap;
#pragma unroll
        for (int ks = 0; ks < 4; ks++)
            a[ks] = *(const bf16x8*)&A[(size_t)rA * 128 + ks * 32 + kb];
    }
#pragma unroll
    for (int c = 0; c < 8; c++) {
        f32x4 acc = {0.f, 0.f, 0.f, 0.f};
#pragma unroll
        for (int ks = 0; ks < 4; ks++) {
            bf16x8 b = *(const bf16x8*)&Bl[((ks * 8 + c) * 64 + lane) * 8];
            acc = __builtin_amdgcn_mfma_f32_16x16x32_bf16(a[ks], b, acc, 0, 0, 0);
        }
        int colb = c * 16 + (lane & 15);
        int rowb = r0 + (lane >> 4) * 4;
#pragma unroll
        for (int r = 0; r < 4; r++)
            C[(size_t)(rowb + r) * 128 + colb] = f2b(acc[r]);
    }
}

// layer-2 GEMM with fused BN-affine + ReLU on A; emits H1 and C = H1 @ W2
__global__ __launch_bounds__(256) void gemm_mfma_bn(const ushort* __restrict__ HB, const float* __restrict__ stats,
                                                    const ushort* __restrict__ WF, ushort* __restrict__ H1,
                                                    ushort* __restrict__ C, int ngrp) {
    __shared__ ushort Bl[4 * 8 * 64 * 8];  // 32 KB
    __shared__ float sst[256];
    sst[threadIdx.x] = stats[threadIdx.x];
    for (int i = threadIdx.x * 8; i < 4 * 8 * 64 * 8; i += 256 * 8)
        *(bf16x8*)&Bl[i] = *(const bf16x8*)&WF[i];
    __syncthreads();
    int wave = __builtin_amdgcn_readfirstlane(threadIdx.x >> 6);
    int lane = threadIdx.x & 63;
    int rg = blockIdx.x * 4 + wave;
    if (rg >= ngrp) return;
    int r0 = rg * 16;
    int rA = r0 + (lane & 15);
    int kb = (lane >> 4) * 8;
    bf16x8 a[4];
#pragma unroll
    for (int ks = 0; ks < 4; ks++) {
        int cbase = ks * 32 + kb;
        bf16x8 u = *(const bf16x8*)&HB[(size_t)rA * 128 + cbase];
        ushort t[8];
#pragma unroll
        for (int e = 0; e < 8; e++) {
            float f = fmaxf(b2f((ushort)u[e]) * sst[cbase + e] + sst[128 + cbase + e], 0.f);
            t[e] = f2b(f);
        }
        a[ks] = *(bf16x8*)t;
        *(bf16x8*)&H1[(size_t)rA * 128 + cbase] = a[ks];
    }
#pragma unroll
    for (int c = 0; c < 8; c++) {
        f32x4 acc = {0.f, 0.f, 0.f, 0.f};
#pragma unroll
        for (int ks = 0; ks < 4; ks++) {
            bf16x8 b = *(const bf16x8*)&Bl[((ks * 8 + c) * 64 + lane) * 8];
            acc = __builtin_amdgcn_mfma_f32_16x16x32_bf16(a[ks], b, acc, 0, 0, 0);
        }
        int colb = c * 16 + (lane & 15);
        int rowb = r0 + (lane >> 4) * 4;
#pragma unroll
        for (int r = 0; r < 4; r++)
            C[(size_t)(rowb + r) * 128 + colb] = f2b(acc[r]);
    }
}

// ---------------- final: OUT[n,64] = max(H1,H2) @ Wf + bf (MFMA) ----------------

__global__ __launch_bounds__(256) void final_mfma(const ushort* __restrict__ H1, const ushort* __restrict__ H2,
                                                  const ushort* __restrict__ WF, const float* __restrict__ bfv,
                                                  float* __restrict__ OUT, int ngrp) {
    __shared__ ushort Bl[4 * 4 * 64 * 8];  // 16 KB
    for (int i = threadIdx.x * 8; i < 4 * 4 * 64 * 8; i += 256 * 8)
        *(bf16x8*)&Bl[i] = *(const bf16x8*)&WF[i];
    __syncthreads();
    int wave = __builtin_amdgcn_readfirstlane(threadIdx.x >> 6);
    int lane = threadIdx.x & 63;
    int rg = blockIdx.x * 4 + wave;
    if (rg >= ngrp) return;
    int r0 = rg * 16;
    int rA = r0 + (lane & 15);
    int kb = (lane >> 4) * 8;
    bf16x8 a[4];
#pragma unroll
    for (int ks = 0; ks < 4; ks++) {
        bf16x8 u = *(const bf16x8*)&H1[(size_t)rA * 128 + ks * 32 + kb];
        bf16x8 v = *(const bf16x8*)&H2[(size_t)rA * 128 + ks * 32 + kb];
        ushort t[8];
#pragma unroll
        for (int e = 0; e < 8; e++) {
            ushort ue = (ushort)u[e], ve = (ushort)v[e];
            t[e] = (b2f(ue) >= b2f(ve)) ? ue : ve;
        }
        a[ks] = *(bf16x8*)t;
    }
#pragma unroll
    for (int c = 0; c < 4; c++) {
        f32x4 acc = {0.f, 0.f, 0.f, 0.f};
#pragma unroll
        for (int ks = 0; ks < 4; ks++) {
            bf16x8 b = *(const bf16x8*)&Bl[((ks * 4 + c) * 64 + lane) * 8];
            acc = __builtin_amdgcn_mfma_f32_16x16x32_bf16(a[ks], b, acc, 0, 0, 0);
        }
        int colb = c * 16 + (lane & 15);
        int rowb = r0 + (lane >> 4) * 4;
        float bb = bfv[colb];
#pragma unroll
        for (int r = 0; r < 4; r++)
            OUT[(size_t)(rowb + r) * 64 + colb] = acc[r] + bb;
    }
}

// ---------------- aggregation: wave = node, 64 lanes = 128 ch, unroll-8 ----------------

__global__ __launch_bounds__(256) void aggregate_b4(const ushort* __restrict__ XW, const int* __restrict__ row,
                                                    const uint* __restrict__ csr4, const float* __restrict__ dinv,
                                                    const float* __restrict__ bias, ushort* __restrict__ OUT, int n) {
    int wave = __builtin_amdgcn_readfirstlane(threadIdx.x >> 6);
    int lane = threadIdx.x & 63;
    int node = blockIdx.x * 4 + wave;
    if (node >= n) return;
    int beg = row[node], end = row[node + 1];
    float ax0 = 0.f, ay0 = 0.f, ax1 = 0.f, ay1 = 0.f;
    int e = beg;
    for (; e + 7 < end; e += 8) {
        uint q0 = __builtin_nontemporal_load(&csr4[e + 0]);
        uint q1 = __builtin_nontemporal_load(&csr4[e + 1]);
        uint q2 = __builtin_nontemporal_load(&csr4[e + 2]);
        uint q3 = __builtin_nontemporal_load(&csr4[e + 3]);
        uint q4 = __builtin_nontemporal_load(&csr4[e + 4]);
        uint q5 = __builtin_nontemporal_load(&csr4[e + 5]);
        uint q6 = __builtin_nontemporal_load(&csr4[e + 6]);
        uint q7 = __builtin_nontemporal_load(&csr4[e + 7]);
        uint v0 = *(const uint*)&XW[(size_t)(q0 & 0x1FFFFu) * 128 + lane * 2];
        uint v1 = *(const uint*)&XW[(size_t)(q1 & 0x1FFFFu) * 128 + lane * 2];
        uint v2 = *(const uint*)&XW[(size_t)(q2 & 0x1FFFFu) * 128 + lane * 2];
        uint v3 = *(const uint*)&XW[(size_t)(q3 & 0x1FFFFu) * 128 + lane * 2];
        uint v4 = *(const uint*)&XW[(size_t)(q4 & 0x1FFFFu) * 128 + lane * 2];
        uint v5 = *(const uint*)&XW[(size_t)(q5 & 0x1FFFFu) * 128 + lane * 2];
        uint v6 = *(const uint*)&XW[(size_t)(q6 & 0x1FFFFu) * 128 + lane * 2];
        uint v7 = *(const uint*)&XW[(size_t)(q7 & 0x1FFFFu) * 128 + lane * 2];
        float w0 = __half2float(__ushort_as_half((ushort)(q0 >> 17)));
        float w1 = __half2float(__ushort_as_half((ushort)(q1 >> 17)));
        float w2 = __half2float(__ushort_as_half((ushort)(q2 >> 17)));
        float w3 = __half2float(__ushort_as_half((ushort)(q3 >> 17)));
        float w4 = __half2float(__ushort_as_half((ushort)(q4 >> 17)));
        float w5 = __half2float(__ushort_as_half((ushort)(q5 >> 17)));
        float w6 = __half2float(__ushort_as_half((ushort)(q6 >> 17)));
        float w7 = __half2float(__ushort_as_half((ushort)(q7 >> 17)));
        ax0 += w0 * __uint_as_float(v0 << 16) + w1 * __uint_as_float(v1 << 16) +
               w2 * __uint_as_float(v2 << 16) + w3 * __uint_as_float(v3 << 16);
        ay0 += w0 * __uint_as_float(v0 & 0xFFFF0000u) + w1 * __uint_as_float(v1 & 0xFFFF0000u) +
               w2 * __uint_as_float(v2 & 0xFFFF0000u) + w3 * __uint_as_float(v3 & 0xFFFF0000u);
        ax1 += w4 * __uint_as_float(v4 << 16) + w5 * __uint_as_float(v5 << 16) +
               w6 * __uint_as_float(v6 << 16) + w7 * __uint_as_float(v7 << 16);
        ay1 += w4 * __uint_as_float(v4 & 0xFFFF0000u) + w5 * __uint_as_float(v5 & 0xFFFF0000u) +
               w6 * __uint_as_float(v6 & 0xFFFF0000u) + w7 * __uint_as_float(v7 & 0xFFFF0000u);
    }
    for (; e < end; e++) {
        uint q0 = __builtin_nontemporal_load(&csr4[e]);
        uint v0 = *(const uint*)&XW[(size_t)(q0 & 0x1FFFFu) * 128 + lane * 2];
        float w0 = __half2float(__ushort_as_half((ushort)(q0 >> 17)));
        ax0 += w0 * __uint_as_float(v0 << 16);
        ay0 += w0 * __uint_as_float(v0 & 0xFFFF0000u);
    }
    float ax = ax0 + ax1, ay = ay0 + ay1;
    float di = dinv[node], sl = di * di;
    uint vs = *(const uint*)&XW[(size_t)node * 128 + lane * 2];
    float ox = ax + sl * __uint_as_float(vs << 16) + bias[lane * 2];
    float oy = ay + sl * __uint_as_float(vs & 0xFFFF0000u) + bias[lane * 2 + 1];
    uint o = (uint)f2b(ox) | ((uint)f2b(oy) << 16);
    *(uint*)&OUT[(size_t)node * 128 + lane * 2] = o;
}

// ---------------- BatchNorm stats ----------------

__global__ __launch_bounds__(256) void bn_stats_b(const ushort* __restrict__ H, float* __restrict__ part, int n) {
    int wave = threadIdx.x >> 6;
    int lane = threadIdx.x & 63;
    float2 s = make_float2(0.f, 0.f), q = make_float2(0.f, 0.f);
    for (int r = blockIdx.x * 4 + wave; r < n; r += gridDim.x * 4) {
        uint v = *(const uint*)&H[(size_t)r * 128 + lane * 2];
        float x = __uint_as_float(v << 16);
        float y = __uint_as_float(v & 0xFFFF0000u);
        s.x += x; s.y += y;
        q.x += x * x; q.y += y * y;
    }
    __shared__ float2 reds[4][64];
    __shared__ float2 redq[4][64];
    reds[wave][lane] = s;
    redq[wave][lane] = q;
    __syncthreads();
    if (threadIdx.x < 64) {
        int l = threadIdx.x;
        float2 S = make_float2(0.f, 0.f), Q = make_float2(0.f, 0.f);
#pragma unroll
        for (int w = 0; w < 4; w++) {
            S.x += reds[w][l].x; S.y += reds[w][l].y;
            Q.x += redq[w][l].x; Q.y += redq[w][l].y;
        }
        part[blockIdx.x * 256 + l * 2 + 0] = S.x;
        part[blockIdx.x * 256 + l * 2 + 1] = S.y;
        part[blockIdx.x * 256 + 128 + l * 2 + 0] = Q.x;
        part[blockIdx.x * 256 + 128 + l * 2 + 1] = Q.y;
    }
}

// parallel final reduction: 1024 threads = 128 channels x 8 groups
__global__ __launch_bounds__(1024) void bn_final2(const float* __restrict__ part, const float* __restrict__ gamma,
                                                  const float* __restrict__ beta, float* __restrict__ stats,
                                                  float invN) {
    int c = threadIdx.x & 127;
    int g = threadIdx.x >> 7;
    float s = 0.f, q = 0.f;
#pragma unroll 8
    for (int b = g; b < 512; b += 8) {
        s += part[b * 256 + c];
        q += part[b * 256 + 128 + c];
    }
    __shared__ float red[8][256];
    red[g][c] = s;
    red[g][128 + c] = q;
    __syncthreads();
    __shared__ float fin[256];
    if (threadIdx.x < 256) {
        float acc = 0.f;
#pragma unroll
        for (int gg = 0; gg < 8; gg++) acc += red[gg][threadIdx.x];
        fin[threadIdx.x] = acc;
    }
    __syncthreads();
    if (threadIdx.x < 128) {
        float mu = fin[c] * invN;
        float var = fin[128 + c] * invN - mu * mu;
        float sc = gamma[c] * rsqrtf(var + EPSF);
        stats[c] = sc;
        stats[128 + c] = beta[c] - mu * sc;
    }
}

// ---------------- launch ----------------

extern "C" void kernel_launch(void* const* d_in, const int* in_sizes, int n_in,
                              void* d_out, int out_size, void* d_ws, size_t ws_size,
                              hipStream_t stream) {
    const float* x     = (const float*)d_in[0];
    const int*   ei    = (const int*)  d_in[1];
    const float* ew    = (const float*)d_in[2];
    const float* W1    = (const float*)d_in[3];
    const float* b1    = (const float*)d_in[4];
    const float* gamma = (const float*)d_in[5];
    const float* beta  = (const float*)d_in[6];
    const float* W2    = (const float*)d_in[7];
    const float* b2    = (const float*)d_in[8];
    const float* Wf    = (const float*)d_in[9];
    const float* bf    = (const float*)d_in[10];
    float* out = (float*)d_out;

    char* ws = (char*)d_ws;
    size_t off = 0;
    auto alloc = [&](size_t bytes) {
        void* p = ws + off;
        off += (bytes + 1023) & ~(size_t)1023;
        return p;
    };
    ushort* XWB  = (ushort*)alloc((size_t)NN * 128 * 2);  // row-major xw; aliased as PART pre-GEMM
    ushort* HB   = (ushort*)alloc((size_t)NN * 128 * 2);
    ushort* H1B  = (ushort*)alloc((size_t)NN * 128 * 2);
    ushort* H2B  = (ushort*)alloc((size_t)NN * 128 * 2);
    float*  DINV = (float*) alloc((size_t)NN * 4);
    int*    ROW  = (int*)   alloc((size_t)(NN + 1) * 4);
    int*    CNT  = (int*)   alloc((size_t)NB * 4);
    int*    BSTART = (int*) alloc((size_t)(NB + 1) * 4);
    uint2*  CSR8 = (uint2*) alloc((size_t)NE * 8);
    uint*   CSR4 = (uint*)  alloc((size_t)NE * 4);
    float*  PARTBN = (float*)alloc((size_t)512 * 256 * 4);
    float*  STAT = (float*) alloc(1024);
    ushort* WF1  = (ushort*)alloc((size_t)4 * 8 * 64 * 8 * 2);
    ushort* WF2  = (ushort*)alloc((size_t)4 * 8 * 64 * 8 * 2);
    ushort* WFF  = (ushort*)alloc((size_t)4 * 4 * 64 * 8 * 2);
    int* PART = (int*)XWB;   // 1.6 MB alias, used only pre-GEMM

    int ngrp = NN / 16;               // 6250
    int gblocks = (ngrp + 3) / 4;     // 1563

    // ---- two-level counting sort (bucket=node>>6), zero global atomics ----
    hist_b<<<NCHUNK, 256, 0, stream>>>(ei, PART);
    scan_chunks_b<<<(NB + 255) / 256, 256, 0, stream>>>(PART, CNT);
    bucket_scan<<<1, 256, 0, stream>>>(CNT, BSTART);
    place_b<<<NCHUNK, 256, 0, stream>>>(ei, ew, BSTART, PART, CSR8);
    subsort<<<NB, 256, 0, stream>>>(CSR8, BSTART, ROW, DINV);
    norm4<<<(NN + 3) / 4, 256, 0, stream>>>(CSR8, ROW, DINV, CSR4, NN);

    pack_w<<<8, 256, 0, stream>>>(W1, WF1, 128);
    pack_w<<<8, 256, 0, stream>>>(W2, WF2, 128);
    pack_w<<<4, 256, 0, stream>>>(Wf, WFF, 64);

    // layer 1
    gemm_mfma<true><<<gblocks, 256, 0, stream>>>(x, WF1, XWB, ngrp);
    aggregate_b4<<<(NN + 3) / 4, 256, 0, stream>>>(XWB, ROW, CSR4, DINV, b1, HB, NN);
    bn_stats_b<<<512, 256, 0, stream>>>(HB, PARTBN, NN);
    bn_final2<<<1, 1024, 0, stream>>>(PARTBN, gamma, beta, STAT, 1.0f / NN);

    // layer 2 (BN+ReLU fused into A-load; emits H1B and XWB = H1 @ W2)
    gemm_mfma_bn<<<gblocks, 256, 0, stream>>>(HB, STAT, WF2, H1B, XWB, ngrp);
    aggregate_b4<<<(NN + 3) / 4, 256, 0, stream>>>(XWB, ROW, CSR4, DINV, b2, H2B, NN);

    // JK max + final projection
    final_mfma<<<gblocks, 256, 0, stream>>>(H1B, H2B, WFF, bf, out, ngrp);
}